// Round 2
// baseline (114.258 us; speedup 1.0000x reference)
//
#include <hip/hip_runtime.h>
#include <cmath>

// pa_lif: T=8, tau=0.25, thresh=0.5. Per-column recurrence (verified round 0,
// initial absmax was 0.0):
//   w[i]   = 0.25*x[i] + 0.75*w[i-1]                      (W_CONST @ x as IIR)
//   p1[i]  = sigmoid(0.5 - 0.5*(0.25*x[i] + w[i]))
//   pre[i] = 0.25*(x[i] + S[i]) - 0.5 ;  out[i] = pre[i] > 0
//   S[i+1] = 0.25*p1[i]*(S[i] + x[i]) ;  S[0] = 0
//
// Round-1 failure was nondeterministic store ordering: float4 fast-path store
// + scalar float refinement store to the same address through differently-typed
// pointers (TBAA says they don't alias -> no enforced ordering). Fix: compute
// everything (incl. rare fp64 refinement) in registers, then ONE float4 store
// per output address. No address-of on register arrays (avoids scratch).

#define TT 8

// one fp32 recurrence step for a single column
#define STEP32(xik, w, S, o)                                  \
    {                                                         \
        float xk = (xik);                                     \
        w = fmaf(0.75f, w, 0.25f * xk);                       \
        float arg = 0.5f - 0.5f * fmaf(0.25f, xk, w);         \
        float p1 = 1.0f / (1.0f + expf(-arg));                \
        float pre = fmaf(0.25f, (xk + S), -0.5f);             \
        o = (pre > 0.0f) ? 1.0f : 0.0f;                       \
        float a = fabsf(pre);                                 \
        mn = (a < mn) ? a : mn;                               \
        S = 0.25f * p1 * (S + xk);                            \
    }

// full fp64 recompute of one column (comp in {x,y,z,w}); constant indices only
#define REFINE64(comp)                                        \
    {                                                         \
        double wd = 0.0, Sd = 0.0;                            \
        _Pragma("unroll")                                     \
        for (int i = 0; i < TT; ++i) {                        \
            double xi = (double)xr[i].comp;                   \
            wd = 0.25 * xi + 0.75 * wd;                       \
            double arg = 0.5 - 0.5 * (0.25 * xi + wd);        \
            double p1 = 1.0 / (1.0 + exp(-arg));              \
            double pre = 0.25 * (xi + Sd) - 0.5;              \
            ot[i].comp = (pre > 0.0) ? 1.0f : 0.0f;           \
            Sd = 0.25 * p1 * (Sd + xi);                       \
        }                                                     \
    }

__global__ __launch_bounds__(256)
void pa_lif_kernel(const float* __restrict__ x, float* __restrict__ out, int dim4) {
    int tid = blockIdx.x * blockDim.x + threadIdx.x;
    if (tid >= dim4) return;

    const float4* __restrict__ xv = (const float4*)x;
    float4* __restrict__ ov = (float4*)out;

    float4 xr[TT];
#pragma unroll
    for (int i = 0; i < TT; ++i) xr[i] = xv[(size_t)i * dim4 + tid];

    float4 ot[TT];
    float w0 = 0.f, w1 = 0.f, w2 = 0.f, w3 = 0.f;
    float S0 = 0.f, S1 = 0.f, S2 = 0.f, S3 = 0.f;
    float mn = 1e30f;

#pragma unroll
    for (int i = 0; i < TT; ++i) {
        STEP32(xr[i].x, w0, S0, ot[i].x);
        STEP32(xr[i].y, w1, S1, ot[i].y);
        STEP32(xr[i].z, w2, S2, ot[i].z);
        STEP32(xr[i].w, w3, S3, ot[i].w);
    }

    // fp32 chain error on pre is ~1e-6; refine the whole thread in fp64 if any
    // of its 32 pre values came within 5e-5 of the threshold (~10% of waves).
    if (mn < 5e-5f) {
        REFINE64(x);
        REFINE64(y);
        REFINE64(z);
        REFINE64(w);
    }

    // single store site per output address -> deterministic final values
#pragma unroll
    for (int i = 0; i < TT; ++i) ov[(size_t)i * dim4 + tid] = ot[i];
}

extern "C" void kernel_launch(void* const* d_in, const int* in_sizes, int n_in,
                              void* d_out, int out_size, void* d_ws, size_t ws_size,
                              hipStream_t stream) {
    (void)n_in; (void)out_size; (void)d_ws; (void)ws_size;
    const float* x = (const float*)d_in[0];
    float* out = (float*)d_out;
    int total = in_sizes[0];        // T * dim = 16,777,216
    int dim = total / TT;           // 2,097,152 columns
    int dim4 = dim / 4;             // 524,288 threads (float4 per thread)
    int block = 256;
    int grid = (dim4 + block - 1) / block;
    pa_lif_kernel<<<grid, block, 0, stream>>>(x, out, dim4);
}

// Round 4
// 110.675 us; speedup vs baseline: 1.0324x; 1.0324x over previous
//
#include <hip/hip_runtime.h>
#include <cmath>

// pa_lif: T=8, tau=0.25, thresh=0.5. Per-column recurrence (absmax 0.0 in R2):
//   w[i]   = 0.25*x[i] + 0.75*w[i-1]                      (W_CONST @ x as IIR)
//   p1[i]  = sigmoid(0.5 - 0.5*(0.25*x[i] + w[i]))
//   pre[i] = 0.25*(x[i] + S[i]) - 0.5 ;  out[i] = pre[i] > 0
//   S[i+1] = 0.25*p1[i]*(S[i] + x[i]) ;  S[0] = 0
//
// Heaviside output: one sign flip = absmax 1.0, so boundary cases (min |pre| <
// 5e-5, ~4% of threads) are recomputed in fp64 (verified exact vs np ref, R2).
// Determinism rule (round-1 lesson): every output address is written by
// EXACTLY ONE store site per launch — fast-store and refine-store are
// exclusive branches, no overwrites.

#define TT 8

// native vector type: __builtin_nontemporal_store requires a real vector,
// not HIP's float4 class
typedef float vfloat4 __attribute__((ext_vector_type(4)));

// one fp32 recurrence step for a single column (tracks min |pre| in `mn`)
#define STEP32(xik, w, S, o)                                  \
    {                                                         \
        float xk_ = (xik);                                    \
        w = fmaf(0.75f, w, 0.25f * xk_);                      \
        float arg_ = 0.5f - 0.5f * fmaf(0.25f, xk_, w);       \
        float p1_ = 1.0f / (1.0f + expf(-arg_));              \
        float pre_ = fmaf(0.25f, (xk_ + S), -0.5f);           \
        o = (pre_ > 0.0f) ? 1.0f : 0.0f;                      \
        float a_ = fabsf(pre_);                               \
        mn = (a_ < mn) ? a_ : mn;                             \
        S = 0.25f * p1_ * (S + xk_);                          \
    }

// one fp64 recurrence step (rare path; matches R2's refine bit-for-bit).
// Unique macro-local names: no shadowing of caller's variables.
#define STEP64(xif, wd, Sd, o)                                \
    {                                                         \
        double xd_ = (double)(xif);                           \
        wd = 0.25 * xd_ + 0.75 * wd;                          \
        double arg_ = 0.5 - 0.5 * (0.25 * xd_ + wd);          \
        double p1_ = 1.0 / (1.0 + exp(-arg_));                \
        double pre_ = 0.25 * (xd_ + Sd) - 0.5;                \
        o = (pre_ > 0.0) ? 1.0f : 0.0f;                       \
        Sd = 0.25 * p1_ * (Sd + xd_);                         \
    }

__global__ __launch_bounds__(256)
void pa_lif_kernel(const float* __restrict__ x, float* __restrict__ out, int dim4) {
    int tid = blockIdx.x * blockDim.x + threadIdx.x;
    if (tid >= dim4) return;

    const float4* __restrict__ xv = (const float4*)x;
    float4* __restrict__ ov = (float4*)out;
    vfloat4* __restrict__ onv = (vfloat4*)out;

    float4 ot[TT];
    float w0 = 0.f, w1 = 0.f, w2 = 0.f, w3 = 0.f;
    float S0 = 0.f, S1 = 0.f, S2 = 0.f, S3 = 0.f;
    float mn = 1e30f;

    // consume each row as it arrives; only ot[] stays live (saves ~32 VGPRs
    // vs staging x[] too — refine branch reloads x instead)
#pragma unroll
    for (int i = 0; i < TT; ++i) {
        float4 xi = xv[(size_t)i * dim4 + tid];
        STEP32(xi.x, w0, S0, ot[i].x);
        STEP32(xi.y, w1, S1, ot[i].y);
        STEP32(xi.z, w2, S2, ot[i].z);
        STEP32(xi.w, w3, S3, ot[i].w);
    }

    if (__builtin_expect(mn >= 5e-5f, 1)) {
        // write-once stream: bypass L2 with nontemporal 16B stores
#pragma unroll
        for (int i = 0; i < TT; ++i) {
            vfloat4 o = {ot[i].x, ot[i].y, ot[i].z, ot[i].w};
            __builtin_nontemporal_store(o, &onv[(size_t)i * dim4 + tid]);
        }
    } else {
        // rare fp64 recompute; reload x (L2/L3-warm), rolled loop keeps the
        // double-exp code small and out of the hot path's register budget
        double wd0 = 0, wd1 = 0, wd2 = 0, wd3 = 0;
        double Sd0 = 0, Sd1 = 0, Sd2 = 0, Sd3 = 0;
#pragma unroll 1
        for (int i = 0; i < TT; ++i) {
            float4 xi = xv[(size_t)i * dim4 + tid];
            float4 o;
            STEP64(xi.x, wd0, Sd0, o.x);
            STEP64(xi.y, wd1, Sd1, o.y);
            STEP64(xi.z, wd2, Sd2, o.z);
            STEP64(xi.w, wd3, Sd3, o.w);
            ov[(size_t)i * dim4 + tid] = o;
        }
    }
}

extern "C" void kernel_launch(void* const* d_in, const int* in_sizes, int n_in,
                              void* d_out, int out_size, void* d_ws, size_t ws_size,
                              hipStream_t stream) {
    (void)n_in; (void)out_size; (void)d_ws; (void)ws_size;
    const float* x = (const float*)d_in[0];
    float* out = (float*)d_out;
    int total = in_sizes[0];        // T * dim = 16,777,216
    int dim = total / TT;           // 2,097,152 columns
    int dim4 = dim / 4;             // 524,288 threads (float4 per thread)
    int block = 256;
    int grid = (dim4 + block - 1) / block;
    pa_lif_kernel<<<grid, block, 0, stream>>>(x, out, dim4);
}